// Round 3
// baseline (643.429 us; speedup 1.0000x reference)
//
#include <hip/hip_runtime.h>
#include <math.h>

// BiDirectionalSymplecticLayer via bf16 MFMA (16x16x32), fp32 state.
// Round 7: revert TRB=64 (FETCH 21->236 MB, HBM thrash, 288us). Back to the
// 177us R0 skeleton (TRB=32, grid 256, dir-loop in-kernel), plus:
//   B-fragment REGISTER PIPELINE: two 16xshort8 buffers (64 VGPR each)
//   ping-pong across the 4 stages; stage k issues stage k+1's weight loads
//   (static matrix cycle W1->W2->W2T->W1T) before its MFMAs+epilogue, so
//   L2 latency/BW hides under compute + barrier instead of serializing at
//   stage start. At 1 block/CU (2 waves/SIMD) we have 256 VGPR/wave free;
//   prev rounds used only 128. Occupancy is pinned (R5/R6 proved it) --
//   spend registers, not TLP.
// Keep: XOR-swizzled bf16 LDS tiles, v_cvt_pk_bf16_f32 f2bf.
// Weights packed to MFMA B-fragment order in d_ws: mat 0=W1,1=W2,2=W2^T,3=W1^T.

#define TRB 32
#define SST 260              // fp32 S row stride (260 % 32 = 4 -> 2-way, free)
#define DTV 0.1f

typedef __attribute__((ext_vector_type(8))) short short8;
typedef __attribute__((ext_vector_type(4))) float float4v;

// Swizzled short-index into a [TRB][256] bf16 tile (matches mm reads).
__device__ __forceinline__ int swz(int row, int col) {
  return row * 256 + (col ^ ((row & 7) << 3));
}

__device__ __forceinline__ unsigned short f2bf(float f) {
  unsigned r;                     // HW RNE f32->bf16 (low 16 of packed result)
  asm("v_cvt_pk_bf16_f32 %0, %1, %1" : "=v"(r) : "v"(f));
  return (unsigned short)r;
}

__device__ __forceinline__ float bf2f(unsigned short b) {
  union { unsigned u; float f; } v; v.u = ((unsigned)b) << 16;
  return v.f;
}

__device__ __forceinline__ float fast_tanh(float x) {
  float ax = fabsf(x);
  float e = __expf(2.0f * ax);
  float t = 1.0f - 2.0f * __builtin_amdgcn_rcpf(e + 1.0f);
  return x < 0.0f ? -t : t;
}

// Fragment order: ws[mat*65536 + ((kc*16+nt)*64+lane)*8 + j] = bf16(W[k][n]),
// k = kc*32 + (lane>>4)*8 + j, n = nt*16 + (lane&15); mats 2,3 use W[n][k].
__global__ void __launch_bounds__(256)
pack_weights(const float* __restrict__ W1, const float* __restrict__ W2,
             unsigned short* __restrict__ ws) {
  __shared__ float tile[32 * 256];
  const int mat = blockIdx.x >> 3, ch = blockIdx.x & 7;
  const float* src = (mat == 0 || mat == 3) ? W1 : W2;
  const bool tr = (mat >= 2);
  for (int i = threadIdx.x; i < 32 * 256; i += 256)   // rows [ch*32, ch*32+32)
    tile[i] = src[ch * 32 * 256 + i];
  __syncthreads();
  const int lane = threadIdx.x & 63;
  const int quad = lane >> 4, l16 = lane & 15;
#pragma unroll
  for (int it = 0; it < 4; ++it) {
    int c = (threadIdx.x >> 6) * 4 + it;   // 0..15
    unsigned short v[8];
    int kc, nt;
    if (!tr) {               // chunk = kc = ch; c enumerates nt
      kc = ch; nt = c;
      int n = nt * 16 + l16;
#pragma unroll
      for (int j = 0; j < 8; ++j) v[j] = f2bf(tile[(quad * 8 + j) * 256 + n]);
    } else {                 // chunk covers n in [ch*32,+32): nt = 2ch + (c&1)
      kc = c >> 1; nt = 2 * ch + (c & 1);
      int nn = (c & 1) * 16 + l16;         // local row in tile
#pragma unroll
      for (int j = 0; j < 8; ++j) v[j] = f2bf(tile[nn * 256 + kc * 32 + quad * 8 + j]);
    }
    unsigned short* dst = ws + ((size_t)mat << 16) + (((kc * 16 + nt) * 64 + lane) << 3);
    *(short8*)dst = *(const short8*)v;
  }
}

// Load this wave's 16 B-fragments (32 cols x K=256) of one matrix into regs.
__device__ __forceinline__ void load_B(const unsigned short* __restrict__ wmat,
                                       int ntb, int lane, short8* B) {
#pragma unroll
  for (int kc = 0; kc < 8; ++kc) {
    B[2 * kc]     = *(const short8*)(wmat + (((kc * 16 + ntb)     * 64 + lane) << 3));
    B[2 * kc + 1] = *(const short8*)(wmat + (((kc * 16 + ntb + 1) * 64 + lane) << 3));
  }
}

// acc[m][t] = A(16m.., :) @ B tiles (preloaded regs), K=256, swizzled A read.
__device__ __forceinline__ void mm_pre(const unsigned short* Asrc, const short8* B,
                                       int lane, float4v acc[2][2]) {
  const int quad = lane >> 4, l16 = lane & 15;
  acc[0][0] = acc[0][1] = acc[1][0] = acc[1][1] = (float4v){0.f, 0.f, 0.f, 0.f};
  const int x0 = (l16 & 7) << 3;           // row-swizzle (row&7 == l16&7)
  const unsigned short* a0 = Asrc + l16 * 256;
  const unsigned short* a1 = Asrc + (l16 + 16) * 256;
#pragma unroll
  for (int kc = 0; kc < 8; ++kc) {
    int off = (quad * 8 + kc * 32) ^ x0;   // 16B-aligned, bijective
    short8 af0 = *(const short8*)(a0 + off);
    short8 af1 = *(const short8*)(a1 + off);
    acc[0][0] = __builtin_amdgcn_mfma_f32_16x16x32_bf16(af0, B[2 * kc],     acc[0][0], 0, 0, 0);
    acc[0][1] = __builtin_amdgcn_mfma_f32_16x16x32_bf16(af0, B[2 * kc + 1], acc[0][1], 0, 0, 0);
    acc[1][0] = __builtin_amdgcn_mfma_f32_16x16x32_bf16(af1, B[2 * kc],     acc[1][0], 0, 0, 0);
    acc[1][1] = __builtin_amdgcn_mfma_f32_16x16x32_bf16(af1, B[2 * kc + 1], acc[1][1], 0, 0, 0);
  }
}

__global__ void __launch_bounds__(512)
symplectic_mfma(const float* __restrict__ x,
                const float* __restrict__ b1, const float* __restrict__ b2,
                const float* __restrict__ Wout,
                const unsigned short* __restrict__ wpack,
                float* __restrict__ out) {
  __shared__ float S[TRB * SST];                            // fp32 state
  __shared__ __align__(16) unsigned short bufS[TRB * 256];  // bf16(S); also g2
  __shared__ __align__(16) unsigned short buf1[TRB * 256];  // h1 / g1

  const int tid = threadIdx.x;
  const int wave = tid >> 6, lane = tid & 63;
  const int quad = lane >> 4, l16 = lane & 15;
  const int b0 = blockIdx.x * TRB;
  const int col0 = wave * 32 + l16;        // tile t adds +16
  const int ntb = wave * 2;

  const float b1v[2] = {b1[col0], b1[col0 + 16]};
  const float b2v[2] = {b2[col0], b2[col0 + 16]};
  const float wov[2] = {Wout[col0], Wout[col0 + 16]};

  short8 BA[16], BB[16];                   // ping-pong B-fragment buffers
  load_B(wpack, ntb, lane, BA);            // W1 for the first L1

  for (int dir = 0; dir < 2; ++dir) {
    const float dt = dir ? -DTV : DTV;
    const float hdt = 0.5f * dt;

    // init S = (q_mid | p_mid), bufS = bf16(S); emit mid cols once
    for (int idx = tid; idx < TRB * 256; idx += 512) {
      int r = idx >> 8, j = idx & 255;
      int b = b0 + r;
      const float* xb = x + ((size_t)(b * 64 + 32) << 7);
      float v = (j < 128) ? xb[j] : (xb[j - 128] - xb[j - 256]);
      S[r * SST + j] = v;
      bufS[swz(r, j)] = f2bf(v);
      if (dir == 0) out[(size_t)b * 768 + 256 + j] = v;
    }
    __syncthreads();

    for (int hs = 0; hs < 8; ++hs) {
      const int half = hs & 1;
      float4v acc[2][2];

      // L1: h1 = tanh(S @ W1 + b1) -> buf1.  Prefetch W2 into BB.
      load_B(wpack + (1 << 16), ntb, lane, BB);
      mm_pre(bufS, BA, lane, acc);
#pragma unroll
      for (int m = 0; m < 2; ++m)
#pragma unroll
        for (int t = 0; t < 2; ++t)
#pragma unroll
          for (int r = 0; r < 4; ++r) {
            int row = m * 16 + quad * 4 + r;
            buf1[swz(row, col0 + t * 16)] = f2bf(fast_tanh(acc[m][t][r] + b1v[t]));
          }
      __syncthreads();

      // L2: g2 = Wout * (1 - tanh(h1 @ W2 + b2)^2) -> bufS (aliased scratch;
      // bf16 state is dead until the L4 epilogue rewrites it).  Prefetch W2^T.
      load_B(wpack + (2 << 16), ntb, lane, BA);
      mm_pre(buf1, BB, lane, acc);
#pragma unroll
      for (int m = 0; m < 2; ++m)
#pragma unroll
        for (int t = 0; t < 2; ++t)
#pragma unroll
          for (int r = 0; r < 4; ++r) {
            int row = m * 16 + quad * 4 + r;
            float h2 = fast_tanh(acc[m][t][r] + b2v[t]);
            bufS[swz(row, col0 + t * 16)] = f2bf(wov[t] * (1.0f - h2 * h2));
          }
      __syncthreads();

      // L3: g1 = (g2 @ W2^T) * (1 - h1^2) -> buf1.  h1 re-read from buf1
      // (each thread reads exactly the element it then overwrites).
      // Prefetch W1^T.
      load_B(wpack + (3 << 16), ntb, lane, BB);
      mm_pre(bufS, BA, lane, acc);
#pragma unroll
      for (int m = 0; m < 2; ++m)
#pragma unroll
        for (int t = 0; t < 2; ++t)
#pragma unroll
          for (int r = 0; r < 4; ++r) {
            int row = m * 16 + quad * 4 + r;
            int ii = swz(row, col0 + t * 16);
            float h = bf2f(buf1[ii]);
            buf1[ii] = f2bf(acc[m][t][r] * (1.0f - h * h));
          }
      __syncthreads();

      // L4: ds = g1 @ W1^T; leapfrog update of S; refresh bf16 mirror.
      // Prefetch W1 for the next hs (or next dir's first L1).
      load_B(wpack, ntb, lane, BA);
      mm_pre(buf1, BB, lane, acc);
      if (wave < 4) {                       // ds cols < 128 -> p -= hdt*ds
#pragma unroll
        for (int m = 0; m < 2; ++m)
#pragma unroll
          for (int t = 0; t < 2; ++t) {
            int tc = col0 + t * 16 + 128;
#pragma unroll
            for (int r = 0; r < 4; ++r) {
              int row = m * 16 + quad * 4 + r;
              float nv = S[row * SST + tc] - hdt * acc[m][t][r];
              S[row * SST + tc] = nv;
              bufS[swz(row, tc)] = f2bf(nv);
            }
          }
      } else {
        if (half == 0) {                    // ds cols >= 128 -> q += dt*ds
#pragma unroll
          for (int m = 0; m < 2; ++m)
#pragma unroll
            for (int t = 0; t < 2; ++t) {
              int tc = col0 + t * 16 - 128;
#pragma unroll
              for (int r = 0; r < 4; ++r) {
                int row = m * 16 + quad * 4 + r;
                float nv = S[row * SST + tc] + dt * acc[m][t][r];
                S[row * SST + tc] = nv;
                bufS[swz(row, tc)] = f2bf(nv);
              }
            }
        } else {                            // q unchanged: restore bf16 mirror
#pragma unroll
          for (int m = 0; m < 2; ++m)
#pragma unroll
            for (int t = 0; t < 2; ++t) {
              int tc = col0 + t * 16 - 128;
#pragma unroll
              for (int r = 0; r < 4; ++r) {
                int row = m * 16 + quad * 4 + r;
                bufS[swz(row, tc)] = f2bf(S[row * SST + tc]);
              }
            }
        }
      }
      __syncthreads();
    }

    const int obase = dir ? 0 : 512;        // fwd -> 512..767, bwd -> 0..255
    for (int idx = tid; idx < TRB * 256; idx += 512) {
      int r = idx >> 8, j = idx & 255;
      out[(size_t)(b0 + r) * 768 + obase + j] = S[r * SST + j];
    }
    __syncthreads();
  }
}

extern "C" void kernel_launch(void* const* d_in, const int* in_sizes, int n_in,
                              void* d_out, int out_size, void* d_ws, size_t ws_size,
                              hipStream_t stream) {
  const float* x    = (const float*)d_in[0];
  const float* W1   = (const float*)d_in[1];
  const float* b1   = (const float*)d_in[2];
  const float* W2   = (const float*)d_in[3];
  const float* b2   = (const float*)d_in[4];
  const float* Wout = (const float*)d_in[5];
  unsigned short* wpack = (unsigned short*)d_ws;   // 4 x 65536 bf16 = 512 KB
  float* out = (float*)d_out;

  hipLaunchKernelGGL(pack_weights, dim3(32), dim3(256), 0, stream, W1, W2, wpack);
  hipLaunchKernelGGL(symplectic_mfma, dim3(8192 / TRB), dim3(512), 0, stream,
                     x, b1, b2, Wout, wpack, out);
}

// Round 4
// 574.742 us; speedup vs baseline: 1.1195x; 1.1195x over previous
//
#include <hip/hip_runtime.h>
#include <math.h>

// BiDirectionalSymplecticLayer via bf16 MFMA (16x16x32), fp32 state.
// Round 8: R2's TRB=64 structure was sound but silently register-clamped:
// plain __launch_bounds__(512) let the compiler target 4 waves/SIMD ->
// 128-VGPR cap -> acc[4][2]+epilogue demand spilled to scratch (FETCH
// 236 MB, HBM 1.16 TB/s). R3's reg-prefetch failed the same way (FETCH
// 412 MB). Fix: __launch_bounds__(512, 2) -> 256-VGPR budget, no spill.
// Occupancy is unchanged (R0-R3 all pinned at 1 block/CU, 2 waves/SIMD).
// Expected: ~32 stages x (2300cyc L2 weight stream amortized over 2x rows)
// -> main dispatch ~115-140us.
// Weights packed to MFMA B-fragment order in d_ws: mat 0=W1,1=W2,2=W2^T,3=W1^T.

#define TRB 64
#define SST 260              // fp32 S row stride (260 % 32 = 4 -> 2-way, free)
#define DTV 0.1f

typedef __attribute__((ext_vector_type(8))) short short8;
typedef __attribute__((ext_vector_type(4))) float float4v;

// Swizzled short-index into a [TRB][256] bf16 tile (matches mm_tiles reads).
__device__ __forceinline__ int swz(int row, int col) {
  return row * 256 + (col ^ ((row & 7) << 3));
}

__device__ __forceinline__ unsigned short f2bf(float f) {
  unsigned r;                     // HW RNE f32->bf16 (low 16 of packed result)
  asm("v_cvt_pk_bf16_f32 %0, %1, %1" : "=v"(r) : "v"(f));
  return (unsigned short)r;
}

__device__ __forceinline__ float bf2f(unsigned short b) {
  union { unsigned u; float f; } v; v.u = ((unsigned)b) << 16;
  return v.f;
}

__device__ __forceinline__ float fast_tanh(float x) {
  float ax = fabsf(x);
  float e = __expf(2.0f * ax);
  float t = 1.0f - 2.0f * __builtin_amdgcn_rcpf(e + 1.0f);
  return x < 0.0f ? -t : t;
}

// Fragment order: ws[mat*65536 + ((kc*16+nt)*64+lane)*8 + j] = bf16(W[k][n]),
// k = kc*32 + (lane>>4)*8 + j, n = nt*16 + (lane&15); mats 2,3 use W[n][k].
__global__ void __launch_bounds__(256)
pack_weights(const float* __restrict__ W1, const float* __restrict__ W2,
             unsigned short* __restrict__ ws) {
  __shared__ float tile[32 * 256];
  const int mat = blockIdx.x >> 3, ch = blockIdx.x & 7;
  const float* src = (mat == 0 || mat == 3) ? W1 : W2;
  const bool tr = (mat >= 2);
  for (int i = threadIdx.x; i < 32 * 256; i += 256)   // rows [ch*32, ch*32+32)
    tile[i] = src[ch * 32 * 256 + i];
  __syncthreads();
  const int lane = threadIdx.x & 63;
  const int quad = lane >> 4, l16 = lane & 15;
#pragma unroll
  for (int it = 0; it < 4; ++it) {
    int c = (threadIdx.x >> 6) * 4 + it;   // 0..15
    unsigned short v[8];
    int kc, nt;
    if (!tr) {               // chunk = kc = ch; c enumerates nt
      kc = ch; nt = c;
      int n = nt * 16 + l16;
#pragma unroll
      for (int j = 0; j < 8; ++j) v[j] = f2bf(tile[(quad * 8 + j) * 256 + n]);
    } else {                 // chunk covers n in [ch*32,+32): nt = 2ch + (c&1)
      kc = c >> 1; nt = 2 * ch + (c & 1);
      int nn = (c & 1) * 16 + l16;         // local row in tile
#pragma unroll
      for (int j = 0; j < 8; ++j) v[j] = f2bf(tile[nn * 256 + kc * 32 + quad * 8 + j]);
    }
    unsigned short* dst = ws + ((size_t)mat << 16) + (((kc * 16 + nt) * 64 + lane) << 3);
    *(short8*)dst = *(const short8*)v;
  }
}

// acc[m][t] += A(16m.., :) @ Wmat(:, wave*32+16t..), K=256, 4 row tiles.
__device__ __forceinline__ void mm_tiles(const unsigned short* Asrc,
                                         const unsigned short* __restrict__ wmat,
                                         int wave, int lane, float4v acc[4][2]) {
  const int quad = lane >> 4, l16 = lane & 15;
#pragma unroll
  for (int m = 0; m < 4; ++m)
#pragma unroll
    for (int t = 0; t < 2; ++t)
      acc[m][t] = (float4v){0.f, 0.f, 0.f, 0.f};
  const int x0 = (l16 & 7) << 3;           // row-swizzle (row&7 == l16&7)
  const int ntb = wave * 2;
#pragma unroll
  for (int kc = 0; kc < 8; ++kc) {
    int off = (quad * 8 + kc * 32) ^ x0;   // 16B-aligned, bijective
    short8 bf0 = *(const short8*)(wmat + (((kc * 16 + ntb) * 64 + lane) << 3));
    short8 bf1 = *(const short8*)(wmat + (((kc * 16 + ntb + 1) * 64 + lane) << 3));
#pragma unroll
    for (int m = 0; m < 4; ++m) {
      short8 af = *(const short8*)(Asrc + (l16 + 16 * m) * 256 + off);
      acc[m][0] = __builtin_amdgcn_mfma_f32_16x16x32_bf16(af, bf0, acc[m][0], 0, 0, 0);
      acc[m][1] = __builtin_amdgcn_mfma_f32_16x16x32_bf16(af, bf1, acc[m][1], 0, 0, 0);
    }
  }
}

__global__ void __launch_bounds__(512, 2)
symplectic_mfma(const float* __restrict__ x,
                const float* __restrict__ b1, const float* __restrict__ b2,
                const float* __restrict__ Wout,
                const unsigned short* __restrict__ wpack,
                float* __restrict__ out) {
  __shared__ float S[TRB * SST];                            // fp32 state 66.5KB
  __shared__ __align__(16) unsigned short bufS[TRB * 256];  // bf16(S); also g2
  __shared__ __align__(16) unsigned short buf1[TRB * 256];  // h1 / g1

  const int tid = threadIdx.x;
  const int wave = tid >> 6, lane = tid & 63;
  const int quad = lane >> 4, l16 = lane & 15;
  const int dir = blockIdx.x & 1;
  const int b0 = (blockIdx.x >> 1) * TRB;
  const int col0 = wave * 32 + l16;        // tile t adds +16

  const float b1v[2] = {b1[col0], b1[col0 + 16]};
  const float b2v[2] = {b2[col0], b2[col0 + 16]};
  const float wov[2] = {Wout[col0], Wout[col0 + 16]};

  const float dt = dir ? -DTV : DTV;
  const float hdt = 0.5f * dt;

  // init S = (q_mid | p_mid), bufS = bf16(S); dir==0 block emits mid cols
  for (int idx = tid; idx < TRB * 256; idx += 512) {
    int r = idx >> 8, j = idx & 255;
    int b = b0 + r;
    const float* xb = x + ((size_t)(b * 64 + 32) << 7);
    float v = (j < 128) ? xb[j] : (xb[j - 128] - xb[j - 256]);
    S[r * SST + j] = v;
    bufS[swz(r, j)] = f2bf(v);
    if (dir == 0) out[(size_t)b * 768 + 256 + j] = v;
  }
  __syncthreads();

  for (int hs = 0; hs < 8; ++hs) {
    const int half = hs & 1;
    float4v acc[4][2];

    // L1: h1 = tanh(S @ W1 + b1) -> buf1
    mm_tiles(bufS, wpack, wave, lane, acc);
#pragma unroll
    for (int m = 0; m < 4; ++m)
#pragma unroll
      for (int t = 0; t < 2; ++t)
#pragma unroll
        for (int r = 0; r < 4; ++r) {
          int row = m * 16 + quad * 4 + r;
          buf1[swz(row, col0 + t * 16)] = f2bf(fast_tanh(acc[m][t][r] + b1v[t]));
        }
    __syncthreads();

    // L2: g2 = Wout * (1 - tanh(h1 @ W2 + b2)^2) -> bufS (aliased scratch;
    // bf16 state is dead until the L4 epilogue rewrites it)
    mm_tiles(buf1, wpack + (1 << 16), wave, lane, acc);
#pragma unroll
    for (int m = 0; m < 4; ++m)
#pragma unroll
      for (int t = 0; t < 2; ++t)
#pragma unroll
        for (int r = 0; r < 4; ++r) {
          int row = m * 16 + quad * 4 + r;
          float h2 = fast_tanh(acc[m][t][r] + b2v[t]);
          bufS[swz(row, col0 + t * 16)] = f2bf(wov[t] * (1.0f - h2 * h2));
        }
    __syncthreads();

    // L3: g1 = (g2 @ W2^T) * (1 - h1^2) -> buf1.  h1 re-read from buf1
    // (each thread reads exactly the element it then overwrites).
    mm_tiles(bufS, wpack + (2 << 16), wave, lane, acc);
#pragma unroll
    for (int m = 0; m < 4; ++m)
#pragma unroll
      for (int t = 0; t < 2; ++t)
#pragma unroll
        for (int r = 0; r < 4; ++r) {
          int row = m * 16 + quad * 4 + r;
          int ii = swz(row, col0 + t * 16);
          float h = bf2f(buf1[ii]);
          buf1[ii] = f2bf(acc[m][t][r] * (1.0f - h * h));
        }
    __syncthreads();

    // L4: ds = g1 @ W1^T; leapfrog update of S; refresh bf16 mirror in bufS
    mm_tiles(buf1, wpack + (3 << 16), wave, lane, acc);
    if (wave < 4) {                       // ds cols < 128 -> p -= hdt*ds
#pragma unroll
      for (int m = 0; m < 4; ++m)
#pragma unroll
        for (int t = 0; t < 2; ++t) {
          int tc = col0 + t * 16 + 128;
#pragma unroll
          for (int r = 0; r < 4; ++r) {
            int row = m * 16 + quad * 4 + r;
            float nv = S[row * SST + tc] - hdt * acc[m][t][r];
            S[row * SST + tc] = nv;
            bufS[swz(row, tc)] = f2bf(nv);
          }
        }
    } else {
      if (half == 0) {                    // ds cols >= 128 -> q += dt*ds
#pragma unroll
        for (int m = 0; m < 4; ++m)
#pragma unroll
          for (int t = 0; t < 2; ++t) {
            int tc = col0 + t * 16 - 128;
#pragma unroll
            for (int r = 0; r < 4; ++r) {
              int row = m * 16 + quad * 4 + r;
              float nv = S[row * SST + tc] + dt * acc[m][t][r];
              S[row * SST + tc] = nv;
              bufS[swz(row, tc)] = f2bf(nv);
            }
          }
      } else {                            // q unchanged: restore bf16 mirror
#pragma unroll
        for (int m = 0; m < 4; ++m)
#pragma unroll
          for (int t = 0; t < 2; ++t) {
            int tc = col0 + t * 16 - 128;
#pragma unroll
            for (int r = 0; r < 4; ++r) {
              int row = m * 16 + quad * 4 + r;
              bufS[swz(row, tc)] = f2bf(S[row * SST + tc]);
            }
          }
      }
    }
    __syncthreads();
  }

  const int obase = dir ? 0 : 512;        // fwd -> 512..767, bwd -> 0..255
  for (int idx = tid; idx < TRB * 256; idx += 512) {
    int r = idx >> 8, j = idx & 255;
    out[(size_t)(b0 + r) * 768 + obase + j] = S[r * SST + j];
  }
}

extern "C" void kernel_launch(void* const* d_in, const int* in_sizes, int n_in,
                              void* d_out, int out_size, void* d_ws, size_t ws_size,
                              hipStream_t stream) {
  const float* x    = (const float*)d_in[0];
  const float* W1   = (const float*)d_in[1];
  const float* b1   = (const float*)d_in[2];
  const float* W2   = (const float*)d_in[3];
  const float* b2   = (const float*)d_in[4];
  const float* Wout = (const float*)d_in[5];
  unsigned short* wpack = (unsigned short*)d_ws;   // 4 x 65536 bf16 = 512 KB
  float* out = (float*)d_out;

  hipLaunchKernelGGL(pack_weights, dim3(32), dim3(256), 0, stream, W1, W2, wpack);
  hipLaunchKernelGGL(symplectic_mfma, dim3((8192 / TRB) * 2), dim3(512), 0, stream,
                     x, b1, b2, Wout, wpack, out);
}

// Round 5
// 574.364 us; speedup vs baseline: 1.1202x; 1.0007x over previous
//
#include <hip/hip_runtime.h>
#include <math.h>

// BiDirectionalSymplecticLayer via bf16 MFMA (16x16x32), fp32 state.
// Round 9: the (512,2) bound changed NOTHING (VGPR 128, FETCH 236 MB, 288us
// == R2). Together with the earlier "(512,4) -> 64 VGPR" data point, hipcc's
// 2nd launch_bounds arg behaves as CUDA min-BLOCKS-per-CU here:
//   (512,4): 32 waves/CU -> 8/SIMD -> 64-VGPR cap
//   (512,2): 16 waves/CU -> 4/SIMD -> 128-VGPR cap  (= default)
//   (512,1):  8 waves/CU -> 2/SIMD -> 256-VGPR cap  <- this round
// TRB=64's acc[4][2] needs ~144 VGPR; under the 128 cap it spills ~8 regs
// -> 512thr x 256blk x 32stages x 2 x 4B ~ 260 MB scratch = the excess
// FETCH. LDS (129 KB) already forces 1 block/CU, so raising the cap costs
// no occupancy. Everything else identical to R8/R2.
// Weights packed to MFMA B-fragment order in d_ws: mat 0=W1,1=W2,2=W2^T,3=W1^T.

#define TRB 64
#define SST 260              // fp32 S row stride (260 % 32 = 4 -> 2-way, free)
#define DTV 0.1f

typedef __attribute__((ext_vector_type(8))) short short8;
typedef __attribute__((ext_vector_type(4))) float float4v;

// Swizzled short-index into a [TRB][256] bf16 tile (matches mm_tiles reads).
__device__ __forceinline__ int swz(int row, int col) {
  return row * 256 + (col ^ ((row & 7) << 3));
}

__device__ __forceinline__ unsigned short f2bf(float f) {
  unsigned r;                     // HW RNE f32->bf16 (low 16 of packed result)
  asm("v_cvt_pk_bf16_f32 %0, %1, %1" : "=v"(r) : "v"(f));
  return (unsigned short)r;
}

__device__ __forceinline__ float bf2f(unsigned short b) {
  union { unsigned u; float f; } v; v.u = ((unsigned)b) << 16;
  return v.f;
}

__device__ __forceinline__ float fast_tanh(float x) {
  float ax = fabsf(x);
  float e = __expf(2.0f * ax);
  float t = 1.0f - 2.0f * __builtin_amdgcn_rcpf(e + 1.0f);
  return x < 0.0f ? -t : t;
}

// Fragment order: ws[mat*65536 + ((kc*16+nt)*64+lane)*8 + j] = bf16(W[k][n]),
// k = kc*32 + (lane>>4)*8 + j, n = nt*16 + (lane&15); mats 2,3 use W[n][k].
__global__ void __launch_bounds__(256)
pack_weights(const float* __restrict__ W1, const float* __restrict__ W2,
             unsigned short* __restrict__ ws) {
  __shared__ float tile[32 * 256];
  const int mat = blockIdx.x >> 3, ch = blockIdx.x & 7;
  const float* src = (mat == 0 || mat == 3) ? W1 : W2;
  const bool tr = (mat >= 2);
  for (int i = threadIdx.x; i < 32 * 256; i += 256)   // rows [ch*32, ch*32+32)
    tile[i] = src[ch * 32 * 256 + i];
  __syncthreads();
  const int lane = threadIdx.x & 63;
  const int quad = lane >> 4, l16 = lane & 15;
#pragma unroll
  for (int it = 0; it < 4; ++it) {
    int c = (threadIdx.x >> 6) * 4 + it;   // 0..15
    unsigned short v[8];
    int kc, nt;
    if (!tr) {               // chunk = kc = ch; c enumerates nt
      kc = ch; nt = c;
      int n = nt * 16 + l16;
#pragma unroll
      for (int j = 0; j < 8; ++j) v[j] = f2bf(tile[(quad * 8 + j) * 256 + n]);
    } else {                 // chunk covers n in [ch*32,+32): nt = 2ch + (c&1)
      kc = c >> 1; nt = 2 * ch + (c & 1);
      int nn = (c & 1) * 16 + l16;         // local row in tile
#pragma unroll
      for (int j = 0; j < 8; ++j) v[j] = f2bf(tile[nn * 256 + kc * 32 + quad * 8 + j]);
    }
    unsigned short* dst = ws + ((size_t)mat << 16) + (((kc * 16 + nt) * 64 + lane) << 3);
    *(short8*)dst = *(const short8*)v;
  }
}

// acc[m][t] += A(16m.., :) @ Wmat(:, wave*32+16t..), K=256, 4 row tiles.
__device__ __forceinline__ void mm_tiles(const unsigned short* Asrc,
                                         const unsigned short* __restrict__ wmat,
                                         int wave, int lane, float4v acc[4][2]) {
  const int quad = lane >> 4, l16 = lane & 15;
#pragma unroll
  for (int m = 0; m < 4; ++m)
#pragma unroll
    for (int t = 0; t < 2; ++t)
      acc[m][t] = (float4v){0.f, 0.f, 0.f, 0.f};
  const int x0 = (l16 & 7) << 3;           // row-swizzle (row&7 == l16&7)
  const int ntb = wave * 2;
#pragma unroll
  for (int kc = 0; kc < 8; ++kc) {
    int off = (quad * 8 + kc * 32) ^ x0;   // 16B-aligned, bijective
    short8 bf0 = *(const short8*)(wmat + (((kc * 16 + ntb) * 64 + lane) << 3));
    short8 bf1 = *(const short8*)(wmat + (((kc * 16 + ntb + 1) * 64 + lane) << 3));
#pragma unroll
    for (int m = 0; m < 4; ++m) {
      short8 af = *(const short8*)(Asrc + (l16 + 16 * m) * 256 + off);
      acc[m][0] = __builtin_amdgcn_mfma_f32_16x16x32_bf16(af, bf0, acc[m][0], 0, 0, 0);
      acc[m][1] = __builtin_amdgcn_mfma_f32_16x16x32_bf16(af, bf1, acc[m][1], 0, 0, 0);
    }
  }
}

__global__ void __launch_bounds__(512, 1)
symplectic_mfma(const float* __restrict__ x,
                const float* __restrict__ b1, const float* __restrict__ b2,
                const float* __restrict__ Wout,
                const unsigned short* __restrict__ wpack,
                float* __restrict__ out) {
  __shared__ float S[TRB * SST];                            // fp32 state 66.5KB
  __shared__ __align__(16) unsigned short bufS[TRB * 256];  // bf16(S); also g2
  __shared__ __align__(16) unsigned short buf1[TRB * 256];  // h1 / g1

  const int tid = threadIdx.x;
  const int wave = tid >> 6, lane = tid & 63;
  const int quad = lane >> 4, l16 = lane & 15;
  const int dir = blockIdx.x & 1;
  const int b0 = (blockIdx.x >> 1) * TRB;
  const int col0 = wave * 32 + l16;        // tile t adds +16

  const float b1v[2] = {b1[col0], b1[col0 + 16]};
  const float b2v[2] = {b2[col0], b2[col0 + 16]};
  const float wov[2] = {Wout[col0], Wout[col0 + 16]};

  const float dt = dir ? -DTV : DTV;
  const float hdt = 0.5f * dt;

  // init S = (q_mid | p_mid), bufS = bf16(S); dir==0 block emits mid cols
  for (int idx = tid; idx < TRB * 256; idx += 512) {
    int r = idx >> 8, j = idx & 255;
    int b = b0 + r;
    const float* xb = x + ((size_t)(b * 64 + 32) << 7);
    float v = (j < 128) ? xb[j] : (xb[j - 128] - xb[j - 256]);
    S[r * SST + j] = v;
    bufS[swz(r, j)] = f2bf(v);
    if (dir == 0) out[(size_t)b * 768 + 256 + j] = v;
  }
  __syncthreads();

  for (int hs = 0; hs < 8; ++hs) {
    const int half = hs & 1;
    float4v acc[4][2];

    // L1: h1 = tanh(S @ W1 + b1) -> buf1
    mm_tiles(bufS, wpack, wave, lane, acc);
#pragma unroll
    for (int m = 0; m < 4; ++m)
#pragma unroll
      for (int t = 0; t < 2; ++t)
#pragma unroll
        for (int r = 0; r < 4; ++r) {
          int row = m * 16 + quad * 4 + r;
          buf1[swz(row, col0 + t * 16)] = f2bf(fast_tanh(acc[m][t][r] + b1v[t]));
        }
    __syncthreads();

    // L2: g2 = Wout * (1 - tanh(h1 @ W2 + b2)^2) -> bufS (aliased scratch;
    // bf16 state is dead until the L4 epilogue rewrites it)
    mm_tiles(buf1, wpack + (1 << 16), wave, lane, acc);
#pragma unroll
    for (int m = 0; m < 4; ++m)
#pragma unroll
      for (int t = 0; t < 2; ++t)
#pragma unroll
        for (int r = 0; r < 4; ++r) {
          int row = m * 16 + quad * 4 + r;
          float h2 = fast_tanh(acc[m][t][r] + b2v[t]);
          bufS[swz(row, col0 + t * 16)] = f2bf(wov[t] * (1.0f - h2 * h2));
        }
    __syncthreads();

    // L3: g1 = (g2 @ W2^T) * (1 - h1^2) -> buf1.  h1 re-read from buf1
    // (each thread reads exactly the element it then overwrites).
    mm_tiles(bufS, wpack + (2 << 16), wave, lane, acc);
#pragma unroll
    for (int m = 0; m < 4; ++m)
#pragma unroll
      for (int t = 0; t < 2; ++t)
#pragma unroll
        for (int r = 0; r < 4; ++r) {
          int row = m * 16 + quad * 4 + r;
          int ii = swz(row, col0 + t * 16);
          float h = bf2f(buf1[ii]);
          buf1[ii] = f2bf(acc[m][t][r] * (1.0f - h * h));
        }
    __syncthreads();

    // L4: ds = g1 @ W1^T; leapfrog update of S; refresh bf16 mirror in bufS
    mm_tiles(buf1, wpack + (3 << 16), wave, lane, acc);
    if (wave < 4) {                       // ds cols < 128 -> p -= hdt*ds
#pragma unroll
      for (int m = 0; m < 4; ++m)
#pragma unroll
        for (int t = 0; t < 2; ++t) {
          int tc = col0 + t * 16 + 128;
#pragma unroll
          for (int r = 0; r < 4; ++r) {
            int row = m * 16 + quad * 4 + r;
            float nv = S[row * SST + tc] - hdt * acc[m][t][r];
            S[row * SST + tc] = nv;
            bufS[swz(row, tc)] = f2bf(nv);
          }
        }
    } else {
      if (half == 0) {                    // ds cols >= 128 -> q += dt*ds
#pragma unroll
        for (int m = 0; m < 4; ++m)
#pragma unroll
          for (int t = 0; t < 2; ++t) {
            int tc = col0 + t * 16 - 128;
#pragma unroll
            for (int r = 0; r < 4; ++r) {
              int row = m * 16 + quad * 4 + r;
              float nv = S[row * SST + tc] + dt * acc[m][t][r];
              S[row * SST + tc] = nv;
              bufS[swz(row, tc)] = f2bf(nv);
            }
          }
      } else {                            // q unchanged: restore bf16 mirror
#pragma unroll
        for (int m = 0; m < 4; ++m)
#pragma unroll
          for (int t = 0; t < 2; ++t) {
            int tc = col0 + t * 16 - 128;
#pragma unroll
            for (int r = 0; r < 4; ++r) {
              int row = m * 16 + quad * 4 + r;
              bufS[swz(row, tc)] = f2bf(S[row * SST + tc]);
            }
          }
      }
    }
    __syncthreads();
  }

  const int obase = dir ? 0 : 512;        // fwd -> 512..767, bwd -> 0..255
  for (int idx = tid; idx < TRB * 256; idx += 512) {
    int r = idx >> 8, j = idx & 255;
    out[(size_t)(b0 + r) * 768 + obase + j] = S[r * SST + j];
  }
}

extern "C" void kernel_launch(void* const* d_in, const int* in_sizes, int n_in,
                              void* d_out, int out_size, void* d_ws, size_t ws_size,
                              hipStream_t stream) {
  const float* x    = (const float*)d_in[0];
  const float* W1   = (const float*)d_in[1];
  const float* b1   = (const float*)d_in[2];
  const float* W2   = (const float*)d_in[3];
  const float* b2   = (const float*)d_in[4];
  const float* Wout = (const float*)d_in[5];
  unsigned short* wpack = (unsigned short*)d_ws;   // 4 x 65536 bf16 = 512 KB
  float* out = (float*)d_out;

  hipLaunchKernelGGL(pack_weights, dim3(32), dim3(256), 0, stream, W1, W2, wpack);
  hipLaunchKernelGGL(symplectic_mfma, dim3((8192 / TRB) * 2), dim3(512), 0, stream,
                     x, b1, b2, Wout, wpack, out);
}

// Round 6
// 571.476 us; speedup vs baseline: 1.1259x; 1.0051x over previous
//
#include <hip/hip_runtime.h>
#include <math.h>

// BiDirectionalSymplecticLayer via bf16 MFMA (16x16x32), fp32 state.
// Round 10: accept the measured envelope -- gfx950 unified RF, compiler
// pins this kernel at 128 VGPR total (R7-R9: launch_bounds ignored, any
// >128 demand spills to scratch; TRB=64 dead). Back to the 177us R0
// config (TRB=32, 512 thr, dir-loop inside, grid 256), plus two changes
// that fit in 128 regs:
//  1) HALF-B REGISTER PREFETCH: persistent Bp[8] (32 VGPR) holds the next
//     stage's kc=0..3 B-fragments, loaded right after the current MFMA
//     loop, BEFORE the epilogue (sched_barrier(0) pins issue order). The
//     compiler's vmcnt(0)-before-s_barrier drain then overlaps the tanh
//     epilogue (~1600 cyc) instead of serializing at next stage's head.
//     Current stage's kc=4..7 frags are inline-loaded and fly under the
//     kc=0..3 MFMAs (those use resident Bp, zero-wait).
//  2) g2 gets its own LDS buffer buf2 (82.5 KB total, still 1 block/CU):
//     bufS bf16 state mirror is never clobbered -> L4's "restore q
//     mirror" VALU branch deleted.
// Weights packed to MFMA B-fragment order in d_ws: mat 0=W1,1=W2,2=W2^T,3=W1^T.

#define TRB 32
#define SST 260              // fp32 S row stride (260 % 32 = 4 -> 2-way, free)
#define DTV 0.1f

typedef __attribute__((ext_vector_type(8))) short short8;
typedef __attribute__((ext_vector_type(4))) float float4v;

// Swizzled short-index into a [TRB][256] bf16 tile (matches mm reads).
__device__ __forceinline__ int swz(int row, int col) {
  return row * 256 + (col ^ ((row & 7) << 3));
}

__device__ __forceinline__ unsigned short f2bf(float f) {
  unsigned r;                     // HW RNE f32->bf16 (low 16 of packed result)
  asm("v_cvt_pk_bf16_f32 %0, %1, %1" : "=v"(r) : "v"(f));
  return (unsigned short)r;
}

__device__ __forceinline__ float bf2f(unsigned short b) {
  union { unsigned u; float f; } v; v.u = ((unsigned)b) << 16;
  return v.f;
}

__device__ __forceinline__ float fast_tanh(float x) {
  float ax = fabsf(x);
  float e = __expf(2.0f * ax);
  float t = 1.0f - 2.0f * __builtin_amdgcn_rcpf(e + 1.0f);
  return x < 0.0f ? -t : t;
}

// Fragment order: ws[mat*65536 + ((kc*16+nt)*64+lane)*8 + j] = bf16(W[k][n]),
// k = kc*32 + (lane>>4)*8 + j, n = nt*16 + (lane&15); mats 2,3 use W[n][k].
__global__ void __launch_bounds__(256)
pack_weights(const float* __restrict__ W1, const float* __restrict__ W2,
             unsigned short* __restrict__ ws) {
  __shared__ float tile[32 * 256];
  const int mat = blockIdx.x >> 3, ch = blockIdx.x & 7;
  const float* src = (mat == 0 || mat == 3) ? W1 : W2;
  const bool tr = (mat >= 2);
  for (int i = threadIdx.x; i < 32 * 256; i += 256)   // rows [ch*32, ch*32+32)
    tile[i] = src[ch * 32 * 256 + i];
  __syncthreads();
  const int lane = threadIdx.x & 63;
  const int quad = lane >> 4, l16 = lane & 15;
#pragma unroll
  for (int it = 0; it < 4; ++it) {
    int c = (threadIdx.x >> 6) * 4 + it;   // 0..15
    unsigned short v[8];
    int kc, nt;
    if (!tr) {               // chunk = kc = ch; c enumerates nt
      kc = ch; nt = c;
      int n = nt * 16 + l16;
#pragma unroll
      for (int j = 0; j < 8; ++j) v[j] = f2bf(tile[(quad * 8 + j) * 256 + n]);
    } else {                 // chunk covers n in [ch*32,+32): nt = 2ch + (c&1)
      kc = c >> 1; nt = 2 * ch + (c & 1);
      int nn = (c & 1) * 16 + l16;         // local row in tile
#pragma unroll
      for (int j = 0; j < 8; ++j) v[j] = f2bf(tile[nn * 256 + kc * 32 + quad * 8 + j]);
    }
    unsigned short* dst = ws + ((size_t)mat << 16) + (((kc * 16 + nt) * 64 + lane) << 3);
    *(short8*)dst = *(const short8*)v;
  }
}

// Prefetch the kc=0..3 half (8 frags, 32 VGPR) of one matrix's wave-slice.
__device__ __forceinline__ void load_Bhalf(const unsigned short* __restrict__ wmat,
                                           int ntb, int lane, short8* Bp) {
#pragma unroll
  for (int kc = 0; kc < 4; ++kc) {
    Bp[2 * kc]     = *(const short8*)(wmat + (((kc * 16 + ntb)     * 64 + lane) << 3));
    Bp[2 * kc + 1] = *(const short8*)(wmat + (((kc * 16 + ntb + 1) * 64 + lane) << 3));
  }
}

// acc[m][t] = A(16m.., :) @ W(:, wave*32+16t..), K=256. kc 0..3 use the
// prefetched Bp (already in regs); kc 4..7 inline-load from L2 (their
// latency hides under the kc 0..3 MFMAs). A read is XOR-swizzled.
__device__ __forceinline__ void mm_mix(const unsigned short* Asrc,
                                       const unsigned short* __restrict__ wmat,
                                       const short8* Bp, int wave, int lane,
                                       float4v acc[2][2]) {
  const int quad = lane >> 4, l16 = lane & 15;
  acc[0][0] = acc[0][1] = acc[1][0] = acc[1][1] = (float4v){0.f, 0.f, 0.f, 0.f};
  const int x0 = (l16 & 7) << 3;           // row-swizzle (row&7 == l16&7)
  const unsigned short* a0 = Asrc + l16 * 256;
  const unsigned short* a1 = Asrc + (l16 + 16) * 256;
  const int ntb = wave * 2;
#pragma unroll
  for (int kc = 0; kc < 8; ++kc) {
    int off = (quad * 8 + kc * 32) ^ x0;   // 16B-aligned, bijective
    short8 af0 = *(const short8*)(a0 + off);
    short8 af1 = *(const short8*)(a1 + off);
    short8 bf0, bf1;
    if (kc < 4) {
      bf0 = Bp[2 * kc];
      bf1 = Bp[2 * kc + 1];
    } else {
      bf0 = *(const short8*)(wmat + (((kc * 16 + ntb)     * 64 + lane) << 3));
      bf1 = *(const short8*)(wmat + (((kc * 16 + ntb + 1) * 64 + lane) << 3));
    }
    acc[0][0] = __builtin_amdgcn_mfma_f32_16x16x32_bf16(af0, bf0, acc[0][0], 0, 0, 0);
    acc[0][1] = __builtin_amdgcn_mfma_f32_16x16x32_bf16(af0, bf1, acc[0][1], 0, 0, 0);
    acc[1][0] = __builtin_amdgcn_mfma_f32_16x16x32_bf16(af1, bf0, acc[1][0], 0, 0, 0);
    acc[1][1] = __builtin_amdgcn_mfma_f32_16x16x32_bf16(af1, bf1, acc[1][1], 0, 0, 0);
  }
}

__global__ void __launch_bounds__(512)
symplectic_mfma(const float* __restrict__ x,
                const float* __restrict__ b1, const float* __restrict__ b2,
                const float* __restrict__ Wout,
                const unsigned short* __restrict__ wpack,
                float* __restrict__ out) {
  __shared__ float S[TRB * SST];                            // fp32 state 33.3KB
  __shared__ __align__(16) unsigned short bufS[TRB * 256];  // bf16(S), persistent
  __shared__ __align__(16) unsigned short buf1[TRB * 256];  // h1 / g1
  __shared__ __align__(16) unsigned short buf2[TRB * 256];  // g2

  const int tid = threadIdx.x;
  const int wave = tid >> 6, lane = tid & 63;
  const int quad = lane >> 4, l16 = lane & 15;
  const int b0 = blockIdx.x * TRB;
  const int col0 = wave * 32 + l16;        // tile t adds +16
  const int ntb = wave * 2;

  const float b1v[2] = {b1[col0], b1[col0 + 16]};
  const float b2v[2] = {b2[col0], b2[col0 + 16]};
  const float wov[2] = {Wout[col0], Wout[col0 + 16]};

  short8 Bp[8];                            // prefetched kc0..3 of next matrix
  load_Bhalf(wpack, ntb, lane, Bp);        // W1-lo for the first L1

  for (int dir = 0; dir < 2; ++dir) {
    const float dt = dir ? -DTV : DTV;
    const float hdt = 0.5f * dt;

    // init S = (q_mid | p_mid), bufS = bf16(S); emit mid cols once
    for (int idx = tid; idx < TRB * 256; idx += 512) {
      int r = idx >> 8, j = idx & 255;
      int b = b0 + r;
      const float* xb = x + ((size_t)(b * 64 + 32) << 7);
      float v = (j < 128) ? xb[j] : (xb[j - 128] - xb[j - 256]);
      S[r * SST + j] = v;
      bufS[swz(r, j)] = f2bf(v);
      if (dir == 0) out[(size_t)b * 768 + 256 + j] = v;
    }
    __syncthreads();

    for (int hs = 0; hs < 8; ++hs) {
      const int half = hs & 1;
      float4v acc[2][2];

      // L1: h1 = tanh(S @ W1 + b1) -> buf1.  Then prefetch W2-lo.
      mm_mix(bufS, wpack, Bp, wave, lane, acc);
      load_Bhalf(wpack + (1 << 16), ntb, lane, Bp);
      __builtin_amdgcn_sched_barrier(0);   // loads issue before epilogue
#pragma unroll
      for (int m = 0; m < 2; ++m)
#pragma unroll
        for (int t = 0; t < 2; ++t)
#pragma unroll
          for (int r = 0; r < 4; ++r) {
            int row = m * 16 + quad * 4 + r;
            buf1[swz(row, col0 + t * 16)] = f2bf(fast_tanh(acc[m][t][r] + b1v[t]));
          }
      __syncthreads();

      // L2: g2 = Wout * (1 - tanh(h1 @ W2 + b2)^2) -> buf2.  Prefetch W2^T-lo.
      mm_mix(buf1, wpack + (1 << 16), Bp, wave, lane, acc);
      load_Bhalf(wpack + (2 << 16), ntb, lane, Bp);
      __builtin_amdgcn_sched_barrier(0);
#pragma unroll
      for (int m = 0; m < 2; ++m)
#pragma unroll
        for (int t = 0; t < 2; ++t)
#pragma unroll
          for (int r = 0; r < 4; ++r) {
            int row = m * 16 + quad * 4 + r;
            float h2 = fast_tanh(acc[m][t][r] + b2v[t]);
            buf2[swz(row, col0 + t * 16)] = f2bf(wov[t] * (1.0f - h2 * h2));
          }
      __syncthreads();

      // L3: g1 = (g2 @ W2^T) * (1 - h1^2) -> buf1 (h1 re-read from buf1;
      // each thread reads exactly the element it then overwrites).
      // Prefetch W1^T-lo.
      mm_mix(buf2, wpack + (2 << 16), Bp, wave, lane, acc);
      load_Bhalf(wpack + (3 << 16), ntb, lane, Bp);
      __builtin_amdgcn_sched_barrier(0);
#pragma unroll
      for (int m = 0; m < 2; ++m)
#pragma unroll
        for (int t = 0; t < 2; ++t)
#pragma unroll
          for (int r = 0; r < 4; ++r) {
            int row = m * 16 + quad * 4 + r;
            int ii = swz(row, col0 + t * 16);
            float h = bf2f(buf1[ii]);
            buf1[ii] = f2bf(acc[m][t][r] * (1.0f - h * h));
          }
      __syncthreads();

      // L4: ds = g1 @ W1^T; leapfrog update; refresh owned bf16 mirror cols.
      // bufS q-cols stay valid when q unchanged (no restore needed).
      // Prefetch W1-lo for next hs / next dir.
      mm_mix(buf1, wpack + (3 << 16), Bp, wave, lane, acc);
      load_Bhalf(wpack, ntb, lane, Bp);
      __builtin_amdgcn_sched_barrier(0);
      if (wave < 4) {                       // ds cols < 128 -> p -= hdt*ds
#pragma unroll
        for (int m = 0; m < 2; ++m)
#pragma unroll
          for (int t = 0; t < 2; ++t) {
            int tc = col0 + t * 16 + 128;
#pragma unroll
            for (int r = 0; r < 4; ++r) {
              int row = m * 16 + quad * 4 + r;
              float nv = S[row * SST + tc] - hdt * acc[m][t][r];
              S[row * SST + tc] = nv;
              bufS[swz(row, tc)] = f2bf(nv);
            }
          }
      } else if (half == 0) {               // ds cols >= 128 -> q += dt*ds
#pragma unroll
        for (int m = 0; m < 2; ++m)
#pragma unroll
          for (int t = 0; t < 2; ++t) {
            int tc = col0 + t * 16 - 128;
#pragma unroll
            for (int r = 0; r < 4; ++r) {
              int row = m * 16 + quad * 4 + r;
              float nv = S[row * SST + tc] + dt * acc[m][t][r];
              S[row * SST + tc] = nv;
              bufS[swz(row, tc)] = f2bf(nv);
            }
          }
      }
      __syncthreads();
    }

    const int obase = dir ? 0 : 512;        // fwd -> 512..767, bwd -> 0..255
    for (int idx = tid; idx < TRB * 256; idx += 512) {
      int r = idx >> 8, j = idx & 255;
      out[(size_t)(b0 + r) * 768 + obase + j] = S[r * SST + j];
    }
    __syncthreads();
  }
}

extern "C" void kernel_launch(void* const* d_in, const int* in_sizes, int n_in,
                              void* d_out, int out_size, void* d_ws, size_t ws_size,
                              hipStream_t stream) {
  const float* x    = (const float*)d_in[0];
  const float* W1   = (const float*)d_in[1];
  const float* b1   = (const float*)d_in[2];
  const float* W2   = (const float*)d_in[3];
  const float* b2   = (const float*)d_in[4];
  const float* Wout = (const float*)d_in[5];
  unsigned short* wpack = (unsigned short*)d_ws;   // 4 x 65536 bf16 = 512 KB
  float* out = (float*)d_out;

  hipLaunchKernelGGL(pack_weights, dim3(32), dim3(256), 0, stream, W1, W2, wpack);
  hipLaunchKernelGGL(symplectic_mfma, dim3(8192 / TRB), dim3(512), 0, stream,
                     x, b1, b2, Wout, wpack, out);
}